// Round 1
// baseline (429.727 us; speedup 1.0000x reference)
//
#include <hip/hip_runtime.h>

#define N_NODES 50000
#define N_EDGES 800000
#define IN_DIM 128
#define OUT_DIM 128
#define N_HEADS 4
#define HEAD_DIM 32
#define LN_EPS 1e-5f

// ws layout (element offsets, 4B elements)
#define WS_H     0          // 6400000 f32
#define WS_ASRC  6400000    // 200000 f32
#define WS_ADST  6600000    // 200000 f32
#define WS_ETAB  6800000    // 16 f32
#define WS_DEG   6800016    // 50000 int
#define WS_OFFS  6850016    // 50001 int (pad to 50004)
#define WS_CUR   6900020    // 50000 int
#define WS_EIDS  6950020    // 800000 int

// ---------------- K1: h = x @ W^T  +  alpha projections -------------------
__global__ __launch_bounds__(256) void gemm_alpha_kernel(
    const float* __restrict__ x, const float* __restrict__ W,
    const float* __restrict__ a_src, const float* __restrict__ a_dst,
    float* __restrict__ h, float* __restrict__ alpha_src, float* __restrict__ alpha_dst)
{
    __shared__ float wt[IN_DIM * OUT_DIM]; // wt[k*128 + d] = W[d][k]  (64 KB)
    for (int i = threadIdx.x; i < IN_DIM * OUT_DIM; i += 256) {
        int d = i >> 7, k = i & 127;
        wt[k * 128 + d] = W[i];
    }
    __syncthreads();
    const float2* wt2 = (const float2*)wt;

    int lane = threadIdx.x & 63;
    int wid  = threadIdx.x >> 6;
    int gw   = blockIdx.x * 4 + wid;
    int nwaves = gridDim.x * 4;
    int head = lane >> 4;
    int hd   = 2 * (lane & 15);
    float ga0 = a_src[head * HEAD_DIM + hd];
    float ga1 = a_src[head * HEAD_DIM + hd + 1];
    float gb0 = a_dst[head * HEAD_DIM + hd];
    float gb1 = a_dst[head * HEAD_DIM + hd + 1];

    for (int n = gw; n < N_NODES; n += nwaves) {
        float2 xv = ((const float2*)(x + (size_t)n * IN_DIM))[lane];
        float accx = 0.f, accy = 0.f;
        #pragma unroll 8
        for (int k2 = 0; k2 < 64; ++k2) {
            float xa = __shfl(xv.x, k2);
            float xb = __shfl(xv.y, k2);
            float2 w0 = wt2[(2 * k2) * 64 + lane];
            float2 w1 = wt2[(2 * k2 + 1) * 64 + lane];
            accx += xa * w0.x + xb * w1.x;
            accy += xa * w0.y + xb * w1.y;
        }
        ((float2*)(h + (size_t)n * OUT_DIM))[lane] = make_float2(accx, accy);
        // alpha partials: reduce over 16-lane head groups
        float pa = accx * ga0 + accy * ga1;
        float pb = accx * gb0 + accy * gb1;
        #pragma unroll
        for (int off = 8; off >= 1; off >>= 1) {
            pa += __shfl_xor(pa, off);
            pb += __shfl_xor(pb, off);
        }
        if ((lane & 15) == 0) {
            alpha_src[n * N_HEADS + head] = pa;
            alpha_dst[n * N_HEADS + head] = pb;
        }
    }
}

// ---------------- etab[t][h] = edge_embed[t] . a_edge[h] ------------------
__global__ void etab_kernel(const float* __restrict__ edge_embed,
                            const float* __restrict__ a_edge,
                            float* __restrict__ etab)
{
    int i = threadIdx.x;
    if (i < 12) {
        int t = i >> 2, hh = i & 3;
        float s = 0.f;
        for (int k = 0; k < 16; ++k) s += edge_embed[t * 16 + k] * a_edge[hh * 16 + k];
        etab[i] = s;
    }
}

// ---------------- CSR build ------------------------------------------------
__global__ void count_kernel(const int* __restrict__ dst, int* __restrict__ deg)
{
    int e = blockIdx.x * 256 + threadIdx.x;
    if (e < N_EDGES) atomicAdd(&deg[dst[e]], 1);
}

__global__ __launch_bounds__(1024) void scan_kernel(const int* __restrict__ deg,
                                                    int* __restrict__ offs)
{
    __shared__ int wsum[16];
    int lane = threadIdx.x & 63;
    int wid  = threadIdx.x >> 6;
    int carry = 0;
    for (int base = 0; base < N_NODES; base += 1024) {
        int i = base + threadIdx.x;
        int v = (i < N_NODES) ? deg[i] : 0;
        int xinc = v;
        #pragma unroll
        for (int d = 1; d < 64; d <<= 1) {
            int y = __shfl_up(xinc, d);
            if (lane >= d) xinc += y;
        }
        if (lane == 63) wsum[wid] = xinc;
        __syncthreads();
        if (wid == 0) {
            int sv = (lane < 16) ? wsum[lane] : 0;
            #pragma unroll
            for (int d = 1; d < 16; d <<= 1) {
                int y = __shfl_up(sv, d);
                if (lane >= d) sv += y;
            }
            if (lane < 16) wsum[lane] = sv;
        }
        __syncthreads();
        int woff = (wid > 0) ? wsum[wid - 1] : 0;
        if (i < N_NODES) offs[i] = carry + woff + xinc - v; // exclusive scan
        int total = wsum[15];
        __syncthreads();
        carry += total;
    }
    if (threadIdx.x == 0) offs[N_NODES] = carry;
}

__global__ void fill_kernel(const int* __restrict__ dst, const int* __restrict__ offs,
                            int* __restrict__ cur, int* __restrict__ eids)
{
    int e = blockIdx.x * 256 + threadIdx.x;
    if (e < N_EDGES) {
        int d = dst[e];
        int p = atomicAdd(&cur[d], 1);
        eids[offs[d] + p] = e;
    }
}

// ---------------- K5: softmax + aggregate + residual + LayerNorm ----------
#define LRELU(c) ((c) > 0.f ? (c) : 0.2f * (c))
#define UPD(m, s, c) { float nm = fmaxf(m, c); s = s * __expf(m - nm) + __expf((c) - nm); m = nm; }
#define COMB(m, s, off) { float om_ = __shfl_xor(m, off); float os_ = __shfl_xor(s, off); \
                          float nm_ = fmaxf(m, om_); \
                          s = s * __expf(m - nm_) + os_ * __expf(om_ - nm_); m = nm_; }

__global__ __launch_bounds__(256) void aggregate_kernel(
    const float* __restrict__ h, const float* __restrict__ alpha_src,
    const float* __restrict__ alpha_dst, const float* __restrict__ etab,
    const int* __restrict__ srcs, const int* __restrict__ etype,
    const int* __restrict__ offs, const int* __restrict__ eids,
    const float* __restrict__ gamma, const float* __restrict__ beta,
    float* __restrict__ out)
{
    int lane = threadIdx.x & 63;
    int wid  = threadIdx.x >> 6;
    int n = blockIdx.x * 4 + wid;
    if (n >= N_NODES) return;
    int head = lane >> 4;

    int e0 = offs[n], e1 = offs[n + 1];
    int deg = e1 - e0;

    float ad0 = alpha_dst[n * 4 + 0], ad1 = alpha_dst[n * 4 + 1];
    float ad2 = alpha_dst[n * 4 + 2], ad3 = alpha_dst[n * 4 + 3];

    // ---- pass 1: per-head online (max, sum) over incoming edges ----
    float m0 = -1e30f, m1 = -1e30f, m2 = -1e30f, m3 = -1e30f;
    float s0 = 0.f, s1 = 0.f, s2 = 0.f, s3 = 0.f;
    for (int j = lane; j < deg; j += 64) {
        int e = eids[e0 + j];
        int si = srcs[e];
        int t  = etype[e];
        float4 as = *(const float4*)(alpha_src + (size_t)si * 4);
        float4 ev = *(const float4*)(etab + t * 4);
        float c0 = LRELU(as.x + ad0 + ev.x);
        float c1 = LRELU(as.y + ad1 + ev.y);
        float c2 = LRELU(as.z + ad2 + ev.z);
        float c3 = LRELU(as.w + ad3 + ev.w);
        UPD(m0, s0, c0); UPD(m1, s1, c1); UPD(m2, s2, c2); UPD(m3, s3, c3);
    }
    #pragma unroll
    for (int off = 32; off >= 1; off >>= 1) {
        COMB(m0, s0, off); COMB(m1, s1, off);
        COMB(m2, s2, off); COMB(m3, s3, off);
    }
    m0 = fmaxf(m0, -1e9f); m1 = fmaxf(m1, -1e9f);
    m2 = fmaxf(m2, -1e9f); m3 = fmaxf(m3, -1e9f);

    float m_h  = (head & 2) ? ((head & 1) ? m3 : m2) : ((head & 1) ? m1 : m0);
    float s_h  = (head & 2) ? ((head & 1) ? s3 : s2) : ((head & 1) ? s1 : s0);
    float ad_h = (head & 2) ? ((head & 1) ? ad3 : ad2) : ((head & 1) ? ad1 : ad0);
    float rs = 1.0f / (s_h + 1e-10f);

    // ---- pass 2: weighted gather-aggregate ----
    const float2* h2 = (const float2*)h;
    float accx = 0.f, accy = 0.f;
    for (int j = 0; j < deg; ++j) {
        int e  = eids[e0 + j];
        int si = srcs[e];
        int t  = etype[e];
        float asv = alpha_src[(size_t)si * 4 + head];
        float c = LRELU(asv + ad_h + etab[t * 4 + head]);
        float w = __expf(c - m_h) * rs;
        float2 hv = h2[(size_t)si * 64 + lane];
        accx += w * hv.x;
        accy += w * hv.y;
    }

    // ---- epilogue: residual + LayerNorm ----
    float2 res = h2[(size_t)n * 64 + lane];
    float ox = accx + res.x, oy = accy + res.y;
    float ssum = ox + oy;
    #pragma unroll
    for (int off = 32; off >= 1; off >>= 1) ssum += __shfl_xor(ssum, off);
    float mean = ssum * (1.0f / 128.0f);
    float dx = ox - mean, dy = oy - mean;
    float vs = dx * dx + dy * dy;
    #pragma unroll
    for (int off = 32; off >= 1; off >>= 1) vs += __shfl_xor(vs, off);
    float inv = rsqrtf(vs * (1.0f / 128.0f) + LN_EPS);
    float2 g = ((const float2*)gamma)[lane];
    float2 b = ((const float2*)beta)[lane];
    float2 o;
    o.x = dx * inv * g.x + b.x;
    o.y = dy * inv * g.y + b.y;
    ((float2*)(out + (size_t)n * OUT_DIM))[lane] = o;
}

// ---------------------------------------------------------------------------
extern "C" void kernel_launch(void* const* d_in, const int* in_sizes, int n_in,
                              void* d_out, int out_size, void* d_ws, size_t ws_size,
                              hipStream_t stream)
{
    const float* x          = (const float*)d_in[0];
    const int*   edge_index = (const int*)d_in[1];
    const int*   etype      = (const int*)d_in[2];
    const float* W          = (const float*)d_in[3];
    const float* a_src      = (const float*)d_in[4];
    const float* a_dst      = (const float*)d_in[5];
    const float* a_edge     = (const float*)d_in[6];
    const float* edge_embed = (const float*)d_in[7];
    const float* gamma      = (const float*)d_in[8];
    const float* beta       = (const float*)d_in[9];

    float* ws   = (float*)d_ws;
    float* h    = ws + WS_H;
    float* asrc = ws + WS_ASRC;
    float* adst = ws + WS_ADST;
    float* etab = ws + WS_ETAB;
    int*   deg  = (int*)d_ws + WS_DEG;
    int*   offs = (int*)d_ws + WS_OFFS;
    int*   cur  = (int*)d_ws + WS_CUR;
    int*   eids = (int*)d_ws + WS_EIDS;

    const int* srcs = edge_index;
    const int* dsts = edge_index + N_EDGES;

    hipMemsetAsync(deg, 0, N_NODES * sizeof(int), stream);
    hipMemsetAsync(cur, 0, N_NODES * sizeof(int), stream);

    etab_kernel<<<1, 64, 0, stream>>>(edge_embed, a_edge, etab);
    gemm_alpha_kernel<<<512, 256, 0, stream>>>(x, W, a_src, a_dst, h, asrc, adst);
    count_kernel<<<(N_EDGES + 255) / 256, 256, 0, stream>>>(dsts, deg);
    scan_kernel<<<1, 1024, 0, stream>>>(deg, offs);
    fill_kernel<<<(N_EDGES + 255) / 256, 256, 0, stream>>>(dsts, offs, cur, eids);
    aggregate_kernel<<<(N_NODES + 3) / 4, 256, 0, stream>>>(
        h, asrc, adst, etab, srcs, etype, offs, eids, gamma, beta, (float*)d_out);
}

// Round 2
// 242.944 us; speedup vs baseline: 1.7688x; 1.7688x over previous
//
#include <hip/hip_runtime.h>

#define N_NODES 50000
#define N_EDGES 800000
#define IN_DIM 128
#define OUT_DIM 128
#define N_HEADS 4
#define HEAD_DIM 32
#define LN_EPS 1e-5f

// ws layout (f32-element offsets)
#define WS_HB    0          // 3,200,000 f32 slots = 6.4M ushort (h in bf16)
#define WS_ASRC  3200000    // 200000 f32
#define WS_ADST  3400000    // 200000 f32
#define WS_ETAB  3600000    // 16 f32
#define WS_DEG   3600016    // 50000 int
#define WS_OFFS  3650016    // 50001 int (pad to 50004)
#define WS_CUR   3700020    // 50000 int
#define WS_PARTS 3750020    // 64 int
#define WS_EIDS  3750084    // 800000 int

#define SCAN_BLOCKS 49      // ceil(50000/1024)

__device__ __forceinline__ unsigned short f2bf(float f) {
    unsigned int u = __float_as_uint(f);
    u += 0x7FFF + ((u >> 16) & 1);          // round-to-nearest-even
    return (unsigned short)(u >> 16);
}
#define BFLO(u) __uint_as_float((unsigned int)(u) << 16)
#define BFHI(u) __uint_as_float((unsigned int)(u) & 0xFFFF0000u)

// ---------------- K1: h(bf16) = x @ W^T  +  alpha projections -------------
__global__ __launch_bounds__(256) void gemm_alpha_kernel(
    const float* __restrict__ x, const float* __restrict__ W,
    const float* __restrict__ a_src, const float* __restrict__ a_dst,
    unsigned short* __restrict__ hb,
    float* __restrict__ alpha_src, float* __restrict__ alpha_dst)
{
    __shared__ float wt[IN_DIM * OUT_DIM];   // wt[k*128 + d] = W[d][k] (64 KB)
    __shared__ float xs[4][2][IN_DIM];       // per-wave 2 staged x rows (4 KB)
    for (int i = threadIdx.x; i < IN_DIM * OUT_DIM; i += 256) {
        int d = i >> 7, k = i & 127;
        wt[k * 128 + d] = W[i];
    }
    __syncthreads();
    const float2* wt2 = (const float2*)wt;

    int lane = threadIdx.x & 63;
    int wid  = threadIdx.x >> 6;
    int gw   = blockIdx.x * 4 + wid;
    int nwaves = gridDim.x * 4;
    int head = lane >> 4;            // dims 2*lane, 2*lane+1 -> head = lane>>4
    int hd   = 2 * (lane & 15);
    float ga0 = a_src[head * HEAD_DIM + hd];
    float ga1 = a_src[head * HEAD_DIM + hd + 1];
    float gb0 = a_dst[head * HEAD_DIM + hd];
    float gb1 = a_dst[head * HEAD_DIM + hd + 1];

    const int npairs = N_NODES / 2;
    for (int p = gw; p < npairs; p += nwaves) {
        int n0 = 2 * p, n1 = n0 + 1;
        ((float2*)xs[wid][0])[lane] = ((const float2*)(x + (size_t)n0 * IN_DIM))[lane];
        ((float2*)xs[wid][1])[lane] = ((const float2*)(x + (size_t)n1 * IN_DIM))[lane];
        // wave-private LDS: no __syncthreads needed (compiler inserts lgkmcnt)
        float a0x = 0.f, a0y = 0.f, a1x = 0.f, a1y = 0.f;
        #pragma unroll 8
        for (int k = 0; k < 128; ++k) {
            float xk0 = xs[wid][0][k];     // LDS broadcast (conflict-free)
            float xk1 = xs[wid][1][k];
            float2 w = wt2[k * 64 + lane];
            a0x += xk0 * w.x; a0y += xk0 * w.y;
            a1x += xk1 * w.x; a1y += xk1 * w.y;
        }
        ushort2 hv0, hv1;
        hv0.x = f2bf(a0x); hv0.y = f2bf(a0y);
        hv1.x = f2bf(a1x); hv1.y = f2bf(a1y);
        ((ushort2*)(hb + (size_t)n0 * OUT_DIM))[lane] = hv0;
        ((ushort2*)(hb + (size_t)n1 * OUT_DIM))[lane] = hv1;

        float pa0 = a0x * ga0 + a0y * ga1;
        float pb0 = a0x * gb0 + a0y * gb1;
        float pa1 = a1x * ga0 + a1y * ga1;
        float pb1 = a1x * gb0 + a1y * gb1;
        #pragma unroll
        for (int off = 8; off >= 1; off >>= 1) {
            pa0 += __shfl_xor(pa0, off); pb0 += __shfl_xor(pb0, off);
            pa1 += __shfl_xor(pa1, off); pb1 += __shfl_xor(pb1, off);
        }
        if ((lane & 15) == 0) {
            alpha_src[n0 * N_HEADS + head] = pa0;
            alpha_dst[n0 * N_HEADS + head] = pb0;
            alpha_src[n1 * N_HEADS + head] = pa1;
            alpha_dst[n1 * N_HEADS + head] = pb1;
        }
    }
}

// ---------------- etab[t][h] = edge_embed[t] . a_edge[h] ------------------
__global__ void etab_kernel(const float* __restrict__ edge_embed,
                            const float* __restrict__ a_edge,
                            float* __restrict__ etab)
{
    int i = threadIdx.x;
    if (i < 12) {
        int t = i >> 2, hh = i & 3;
        float s = 0.f;
        for (int k = 0; k < 16; ++k) s += edge_embed[t * 16 + k] * a_edge[hh * 16 + k];
        etab[i] = s;
    }
}

// ---------------- CSR build ------------------------------------------------
__global__ void count_kernel(const int* __restrict__ dst, int* __restrict__ deg)
{
    int e = blockIdx.x * 256 + threadIdx.x;
    if (e < N_EDGES) atomicAdd(&deg[dst[e]], 1);
}

__global__ __launch_bounds__(1024) void scan_part_kernel(
    const int* __restrict__ deg, int* __restrict__ offs, int* __restrict__ parts)
{
    __shared__ int wsum[16];
    int i = blockIdx.x * 1024 + threadIdx.x;
    int lane = threadIdx.x & 63;
    int wid  = threadIdx.x >> 6;
    int v = (i < N_NODES) ? deg[i] : 0;
    int xinc = v;
    #pragma unroll
    for (int d = 1; d < 64; d <<= 1) {
        int y = __shfl_up(xinc, d);
        if (lane >= d) xinc += y;
    }
    if (lane == 63) wsum[wid] = xinc;
    __syncthreads();
    if (wid == 0) {
        int sv = (lane < 16) ? wsum[lane] : 0;
        #pragma unroll
        for (int d = 1; d < 16; d <<= 1) {
            int y = __shfl_up(sv, d);
            if (lane >= d) sv += y;
        }
        if (lane < 16) wsum[lane] = sv;
    }
    __syncthreads();
    int woff = (wid > 0) ? wsum[wid - 1] : 0;
    if (i < N_NODES) offs[i] = woff + xinc - v;   // tile-local exclusive
    if (threadIdx.x == 0) parts[blockIdx.x] = wsum[15];
}

__global__ void scan_tops_kernel(int* __restrict__ parts, int* __restrict__ offs_last)
{
    int lane = threadIdx.x;  // 64 threads
    int v = (lane < SCAN_BLOCKS) ? parts[lane] : 0;
    int xv = v;
    #pragma unroll
    for (int d = 1; d < 64; d <<= 1) {
        int y = __shfl_up(xv, d);
        if (lane >= d) xv += y;
    }
    if (lane < SCAN_BLOCKS) parts[lane] = xv - v;  // exclusive
    if (lane == 63) *offs_last = xv;               // grand total
}

__global__ __launch_bounds__(1024) void scan_add_kernel(
    int* __restrict__ offs, const int* __restrict__ parts)
{
    int i = blockIdx.x * 1024 + threadIdx.x;
    if (i < N_NODES) offs[i] += parts[blockIdx.x];
}

__global__ void fill_kernel(const int* __restrict__ dst, const int* __restrict__ offs,
                            int* __restrict__ cur, int* __restrict__ eids)
{
    int e = blockIdx.x * 256 + threadIdx.x;
    if (e < N_EDGES) {
        int d = dst[e];
        int p = atomicAdd(&cur[d], 1);
        eids[offs[d] + p] = e;
    }
}

// ---------------- K5: softmax + aggregate + residual + LayerNorm ----------
#define LRELU(c) ((c) > 0.f ? (c) : 0.2f * (c))
#define UPD(m, s, c) { float nm = fmaxf(m, c); s = s * __expf(m - nm) + __expf((c) - nm); m = nm; }
#define COMB(m, s, off) { float om_ = __shfl_xor(m, off); float os_ = __shfl_xor(s, off); \
                          float nm_ = fmaxf(m, om_); \
                          s = s * __expf(m - nm_) + os_ * __expf(om_ - nm_); m = nm_; }

__global__ __launch_bounds__(256) void aggregate_kernel(
    const unsigned short* __restrict__ hb, const float* __restrict__ alpha_src,
    const float* __restrict__ alpha_dst, const float* __restrict__ etab,
    const int* __restrict__ srcs, const int* __restrict__ etype,
    const int* __restrict__ offs, const int* __restrict__ eids,
    const float* __restrict__ gamma, const float* __restrict__ beta,
    float* __restrict__ out)
{
    int lane = threadIdx.x & 63;
    int wid  = threadIdx.x >> 6;
    int n = blockIdx.x * 4 + wid;
    if (n >= N_NODES) return;

    int e0 = offs[n], deg = offs[n + 1] - e0;

    float4 adv = *(const float4*)(alpha_dst + (size_t)n * 4);
    float ad0 = adv.x, ad1 = adv.y, ad2 = adv.z, ad3 = adv.w;

    // ---- pass 1: per-head online (max, sum), lane-parallel over edges ----
    float m0 = -1e30f, m1 = -1e30f, m2 = -1e30f, m3 = -1e30f;
    float s0 = 0.f, s1 = 0.f, s2 = 0.f, s3 = 0.f;
    for (int j = lane; j < deg; j += 64) {
        int e = eids[e0 + j];
        int si = srcs[e];
        int t  = etype[e];
        float4 as = *(const float4*)(alpha_src + (size_t)si * 4);
        float4 ev = *(const float4*)(etab + t * 4);
        float c0 = LRELU(as.x + ad0 + ev.x);
        float c1 = LRELU(as.y + ad1 + ev.y);
        float c2 = LRELU(as.z + ad2 + ev.z);
        float c3 = LRELU(as.w + ad3 + ev.w);
        UPD(m0, s0, c0); UPD(m1, s1, c1); UPD(m2, s2, c2); UPD(m3, s3, c3);
    }
    #pragma unroll
    for (int off = 32; off >= 1; off >>= 1) {
        COMB(m0, s0, off); COMB(m1, s1, off);
        COMB(m2, s2, off); COMB(m3, s3, off);
    }
    m0 = fmaxf(m0, -1e9f); m1 = fmaxf(m1, -1e9f);
    m2 = fmaxf(m2, -1e9f); m3 = fmaxf(m3, -1e9f);

    // ---- pass 2: 4 edge-groups of 16 lanes; lane owns 8 dims ----
    int g  = lane >> 4;          // edge group 0..3
    int sl = lane & 15;          // sub-lane: dims sl*8 .. sl*8+7
    int headL = sl >> 2;         // head of this lane's dims

    float m_h  = (headL & 2) ? ((headL & 1) ? m3 : m2) : ((headL & 1) ? m1 : m0);
    float s_h  = (headL & 2) ? ((headL & 1) ? s3 : s2) : ((headL & 1) ? s1 : s0);
    float ad_h = (headL & 2) ? ((headL & 1) ? ad3 : ad2) : ((headL & 1) ? ad1 : ad0);
    float rs = 1.0f / (s_h + 1e-10f);
    float et0 = etab[0 * 4 + headL];
    float et1 = etab[1 * 4 + headL];
    float et2 = etab[2 * 4 + headL];

    float acc[8];
    #pragma unroll
    for (int k = 0; k < 8; ++k) acc[k] = 0.f;

    for (int j = g; j < deg; j += 4) {
        int e  = eids[e0 + j];
        int si = srcs[e];
        int t  = etype[e];
        float asv = alpha_src[(size_t)si * 4 + headL];
        float ev  = (t == 0) ? et0 : ((t == 1) ? et1 : et2);
        float c = LRELU(asv + ad_h + ev);
        float w = __expf(c - m_h) * rs;
        uint4 hv = *(const uint4*)(hb + ((size_t)si << 7) + (sl << 3));
        acc[0] += w * BFLO(hv.x); acc[1] += w * BFHI(hv.x);
        acc[2] += w * BFLO(hv.y); acc[3] += w * BFHI(hv.y);
        acc[4] += w * BFLO(hv.z); acc[5] += w * BFHI(hv.z);
        acc[6] += w * BFLO(hv.w); acc[7] += w * BFHI(hv.w);
    }
    // combine the 4 edge-groups
    #pragma unroll
    for (int k = 0; k < 8; ++k) {
        acc[k] += __shfl_xor(acc[k], 16);
        acc[k] += __shfl_xor(acc[k], 32);
    }

    // ---- epilogue: residual + LayerNorm (8 dims per lane, dup x4) ----
    uint4 rv = *(const uint4*)(hb + ((size_t)n << 7) + (sl << 3));
    float o[8];
    o[0] = acc[0] + BFLO(rv.x); o[1] = acc[1] + BFHI(rv.x);
    o[2] = acc[2] + BFLO(rv.y); o[3] = acc[3] + BFHI(rv.y);
    o[4] = acc[4] + BFLO(rv.z); o[5] = acc[5] + BFHI(rv.z);
    o[6] = acc[6] + BFLO(rv.w); o[7] = acc[7] + BFHI(rv.w);

    float lsum = 0.f;
    #pragma unroll
    for (int k = 0; k < 8; ++k) lsum += o[k];
    #pragma unroll
    for (int off = 8; off >= 1; off >>= 1) lsum += __shfl_xor(lsum, off);
    float mean = lsum * (1.0f / 128.0f);
    float vs = 0.f;
    #pragma unroll
    for (int k = 0; k < 8; ++k) { float d = o[k] - mean; vs += d * d; }
    #pragma unroll
    for (int off = 8; off >= 1; off >>= 1) vs += __shfl_xor(vs, off);
    float inv = rsqrtf(vs * (1.0f / 128.0f) + LN_EPS);

    float4 g0 = *(const float4*)(gamma + sl * 8);
    float4 g1 = *(const float4*)(gamma + sl * 8 + 4);
    float4 b0 = *(const float4*)(beta + sl * 8);
    float4 b1 = *(const float4*)(beta + sl * 8 + 4);
    float gg[8] = {g0.x, g0.y, g0.z, g0.w, g1.x, g1.y, g1.z, g1.w};
    float bb[8] = {b0.x, b0.y, b0.z, b0.w, b1.x, b1.y, b1.z, b1.w};
    float fin[8];
    #pragma unroll
    for (int k = 0; k < 8; ++k) fin[k] = (o[k] - mean) * inv * gg[k] + bb[k];

    // each lane writes its group's float2 slice -> full 128-dim coverage
    float2 wv; wv.x = fin[2 * g]; wv.y = fin[2 * g + 1];
    *(float2*)(out + (size_t)n * OUT_DIM + sl * 8 + 2 * g) = wv;
}

// ---------------------------------------------------------------------------
extern "C" void kernel_launch(void* const* d_in, const int* in_sizes, int n_in,
                              void* d_out, int out_size, void* d_ws, size_t ws_size,
                              hipStream_t stream)
{
    const float* x          = (const float*)d_in[0];
    const int*   edge_index = (const int*)d_in[1];
    const int*   etype      = (const int*)d_in[2];
    const float* W          = (const float*)d_in[3];
    const float* a_src      = (const float*)d_in[4];
    const float* a_dst      = (const float*)d_in[5];
    const float* a_edge     = (const float*)d_in[6];
    const float* edge_embed = (const float*)d_in[7];
    const float* gamma      = (const float*)d_in[8];
    const float* beta       = (const float*)d_in[9];

    float* ws = (float*)d_ws;
    unsigned short* hb = (unsigned short*)(ws + WS_HB);
    float* asrc = ws + WS_ASRC;
    float* adst = ws + WS_ADST;
    float* etab = ws + WS_ETAB;
    int*   deg  = (int*)d_ws + WS_DEG;
    int*   offs = (int*)d_ws + WS_OFFS;
    int*   cur  = (int*)d_ws + WS_CUR;
    int*   parts= (int*)d_ws + WS_PARTS;
    int*   eids = (int*)d_ws + WS_EIDS;

    const int* srcs = edge_index;
    const int* dsts = edge_index + N_EDGES;

    hipMemsetAsync(deg, 0, N_NODES * sizeof(int), stream);
    hipMemsetAsync(cur, 0, N_NODES * sizeof(int), stream);

    etab_kernel<<<1, 64, 0, stream>>>(edge_embed, a_edge, etab);
    gemm_alpha_kernel<<<512, 256, 0, stream>>>(x, W, a_src, a_dst, hb, asrc, adst);
    count_kernel<<<(N_EDGES + 255) / 256, 256, 0, stream>>>(dsts, deg);
    scan_part_kernel<<<SCAN_BLOCKS, 1024, 0, stream>>>(deg, offs, parts);
    scan_tops_kernel<<<1, 64, 0, stream>>>(parts, offs + N_NODES);
    scan_add_kernel<<<SCAN_BLOCKS, 1024, 0, stream>>>(offs, parts);
    fill_kernel<<<(N_EDGES + 255) / 256, 256, 0, stream>>>(dsts, offs, cur, eids);
    aggregate_kernel<<<(N_NODES + 3) / 4, 256, 0, stream>>>(
        hb, asrc, adst, etab, srcs, etype, offs, eids, gamma, beta, (float*)d_out);
}

// Round 3
// 198.755 us; speedup vs baseline: 2.1621x; 1.2223x over previous
//
#include <hip/hip_runtime.h>

#define N_NODES 50000
#define N_EDGES 800000
#define IN_DIM 128
#define OUT_DIM 128
#define N_HEADS 4
#define HEAD_DIM 32
#define LN_EPS 1e-5f

// ws layout (f32-element offsets)
#define WS_HB    0          // 3,200,000 f32 slots = 6.4M ushort (h in bf16)
#define WS_ASRC  3200000    // 200000 f32
#define WS_ADST  3400000    // 200000 f32
#define WS_ETAB  3600000    // 16 f32
#define WS_DEG   3600016    // 50000 int
#define WS_CUR   3650016    // 50000 int  (contiguous with DEG: one memset)
#define WS_OFFS  3700016    // 50001 int (pad to 50004)
#define WS_PARTS 3750020    // 64 int
#define WS_EPACK 3750084    // 800000 u32 (src | etype<<16, sorted by dst)

#define SCAN_BLOCKS 49      // ceil(50000/1024)

__device__ __forceinline__ unsigned short f2bf(float f) {
    unsigned int u = __float_as_uint(f);
    u += 0x7FFF + ((u >> 16) & 1);          // round-to-nearest-even
    return (unsigned short)(u >> 16);
}
#define BFLO(u) __uint_as_float((unsigned int)(u) << 16)
#define BFHI(u) __uint_as_float((unsigned int)(u) & 0xFFFF0000u)

// ---------------- K1: h(bf16) = x @ W^T  +  alpha projections -------------
__global__ __launch_bounds__(256) void gemm_alpha_kernel(
    const float* __restrict__ x, const float* __restrict__ W,
    const float* __restrict__ a_src, const float* __restrict__ a_dst,
    unsigned short* __restrict__ hb,
    float* __restrict__ alpha_src, float* __restrict__ alpha_dst)
{
    __shared__ float wt[IN_DIM * OUT_DIM];   // wt[k*128 + d] = W[d][k] (64 KB)
    __shared__ float xs[4][2][IN_DIM];       // per-wave 2 staged x rows (4 KB)
    for (int i = threadIdx.x; i < IN_DIM * OUT_DIM; i += 256) {
        int d = i >> 7, k = i & 127;
        wt[k * 128 + d] = W[i];
    }
    __syncthreads();
    const float2* wt2 = (const float2*)wt;

    int lane = threadIdx.x & 63;
    int wid  = threadIdx.x >> 6;
    int gw   = blockIdx.x * 4 + wid;
    int nwaves = gridDim.x * 4;
    int head = lane >> 4;
    int hd   = 2 * (lane & 15);
    float ga0 = a_src[head * HEAD_DIM + hd];
    float ga1 = a_src[head * HEAD_DIM + hd + 1];
    float gb0 = a_dst[head * HEAD_DIM + hd];
    float gb1 = a_dst[head * HEAD_DIM + hd + 1];

    const int npairs = N_NODES / 2;
    for (int p = gw; p < npairs; p += nwaves) {
        int n0 = 2 * p, n1 = n0 + 1;
        ((float2*)xs[wid][0])[lane] = ((const float2*)(x + (size_t)n0 * IN_DIM))[lane];
        ((float2*)xs[wid][1])[lane] = ((const float2*)(x + (size_t)n1 * IN_DIM))[lane];
        float a0x = 0.f, a0y = 0.f, a1x = 0.f, a1y = 0.f;
        #pragma unroll 8
        for (int k = 0; k < 128; ++k) {
            float xk0 = xs[wid][0][k];
            float xk1 = xs[wid][1][k];
            float2 w = wt2[k * 64 + lane];
            a0x += xk0 * w.x; a0y += xk0 * w.y;
            a1x += xk1 * w.x; a1y += xk1 * w.y;
        }
        ushort2 hv0, hv1;
        hv0.x = f2bf(a0x); hv0.y = f2bf(a0y);
        hv1.x = f2bf(a1x); hv1.y = f2bf(a1y);
        ((ushort2*)(hb + (size_t)n0 * OUT_DIM))[lane] = hv0;
        ((ushort2*)(hb + (size_t)n1 * OUT_DIM))[lane] = hv1;

        float pa0 = a0x * ga0 + a0y * ga1;
        float pb0 = a0x * gb0 + a0y * gb1;
        float pa1 = a1x * ga0 + a1y * ga1;
        float pb1 = a1x * gb0 + a1y * gb1;
        #pragma unroll
        for (int off = 8; off >= 1; off >>= 1) {
            pa0 += __shfl_xor(pa0, off); pb0 += __shfl_xor(pb0, off);
            pa1 += __shfl_xor(pa1, off); pb1 += __shfl_xor(pb1, off);
        }
        if ((lane & 15) == 0) {
            alpha_src[n0 * N_HEADS + head] = pa0;
            alpha_dst[n0 * N_HEADS + head] = pb0;
            alpha_src[n1 * N_HEADS + head] = pa1;
            alpha_dst[n1 * N_HEADS + head] = pb1;
        }
    }
}

// ---------------- CSR build (count + fused etab) ---------------------------
__global__ void count_kernel(const int* __restrict__ dst, int* __restrict__ deg,
                             const float* __restrict__ edge_embed,
                             const float* __restrict__ a_edge,
                             float* __restrict__ etab)
{
    if (blockIdx.x == 0 && threadIdx.x < 12) {
        int t = threadIdx.x >> 2, hh = threadIdx.x & 3;
        float s = 0.f;
        for (int k = 0; k < 16; ++k) s += edge_embed[t * 16 + k] * a_edge[hh * 16 + k];
        etab[threadIdx.x] = s;
    }
    int e = blockIdx.x * 256 + threadIdx.x;
    if (e < N_EDGES) atomicAdd(&deg[dst[e]], 1);
}

__global__ __launch_bounds__(1024) void scan_part_kernel(
    const int* __restrict__ deg, int* __restrict__ offs, int* __restrict__ parts)
{
    __shared__ int wsum[16];
    int i = blockIdx.x * 1024 + threadIdx.x;
    int lane = threadIdx.x & 63;
    int wid  = threadIdx.x >> 6;
    int v = (i < N_NODES) ? deg[i] : 0;
    int xinc = v;
    #pragma unroll
    for (int d = 1; d < 64; d <<= 1) {
        int y = __shfl_up(xinc, d);
        if (lane >= d) xinc += y;
    }
    if (lane == 63) wsum[wid] = xinc;
    __syncthreads();
    if (wid == 0) {
        int sv = (lane < 16) ? wsum[lane] : 0;
        #pragma unroll
        for (int d = 1; d < 16; d <<= 1) {
            int y = __shfl_up(sv, d);
            if (lane >= d) sv += y;
        }
        if (lane < 16) wsum[lane] = sv;
    }
    __syncthreads();
    int woff = (wid > 0) ? wsum[wid - 1] : 0;
    if (i < N_NODES) offs[i] = woff + xinc - v;   // tile-local exclusive
    if (threadIdx.x == 0) parts[blockIdx.x] = wsum[15];
}

__global__ void scan_tops_kernel(int* __restrict__ parts, int* __restrict__ offs_last)
{
    int lane = threadIdx.x;  // 64 threads
    int v = (lane < SCAN_BLOCKS) ? parts[lane] : 0;
    int xv = v;
    #pragma unroll
    for (int d = 1; d < 64; d <<= 1) {
        int y = __shfl_up(xv, d);
        if (lane >= d) xv += y;
    }
    if (lane < SCAN_BLOCKS) parts[lane] = xv - v;  // exclusive
    if (lane == 63) *offs_last = xv;               // grand total
}

__global__ __launch_bounds__(1024) void scan_add_kernel(
    int* __restrict__ offs, const int* __restrict__ parts)
{
    int i = blockIdx.x * 1024 + threadIdx.x;
    if (i < N_NODES) offs[i] += parts[blockIdx.x];
}

__global__ void fill_kernel(const int* __restrict__ srcs, const int* __restrict__ dsts,
                            const int* __restrict__ etype,
                            const int* __restrict__ offs,
                            int* __restrict__ cur, unsigned int* __restrict__ epack)
{
    int e = blockIdx.x * 256 + threadIdx.x;
    if (e < N_EDGES) {
        int d = dsts[e];
        int p = atomicAdd(&cur[d], 1);
        epack[offs[d] + p] = (unsigned int)srcs[e] | ((unsigned int)etype[e] << 16);
    }
}

// ---------------- K5: softmax + aggregate + residual + LayerNorm ----------
#define LRELU(c) ((c) > 0.f ? (c) : 0.2f * (c))
#define UPD(m, s, c) { float nm = fmaxf(m, c); s = s * __expf(m - nm) + __expf((c) - nm); m = nm; }
#define COMB(m, s, off) { float om_ = __shfl_xor(m, off); float os_ = __shfl_xor(s, off); \
                          float nm_ = fmaxf(m, om_); \
                          s = s * __expf(m - nm_) + os_ * __expf(om_ - nm_); m = nm_; }

__global__ __launch_bounds__(256) void aggregate_kernel(
    const unsigned short* __restrict__ hb, const float* __restrict__ alpha_src,
    const float* __restrict__ alpha_dst, const float* __restrict__ etab,
    const unsigned int* __restrict__ epack, const int* __restrict__ offs,
    const float* __restrict__ gamma, const float* __restrict__ beta,
    float* __restrict__ out)
{
    int lane = threadIdx.x & 63;
    int wid  = threadIdx.x >> 6;
    int half = lane >> 5;              // two nodes per wave
    int l5   = lane & 31;
    int n = blockIdx.x * 8 + wid * 2 + half;
    if (n >= N_NODES) return;

    int e0 = offs[n], deg = offs[n + 1] - e0;

    float4 adv = *(const float4*)(alpha_dst + (size_t)n * 4);
    float ad0 = adv.x, ad1 = adv.y, ad2 = adv.z, ad3 = adv.w;

    // ---- pass 1: per-head online (max, sum), 32 lanes over edges ----
    float m0 = -1e30f, m1 = -1e30f, m2 = -1e30f, m3 = -1e30f;
    float s0 = 0.f, s1 = 0.f, s2 = 0.f, s3 = 0.f;
    for (int j = l5; j < deg; j += 32) {
        unsigned int p = epack[e0 + j];
        int si = p & 0xFFFF;
        int t  = p >> 16;
        float4 as = *(const float4*)(alpha_src + (size_t)si * 4);
        float4 ev = *(const float4*)(etab + t * 4);
        float c0 = LRELU(as.x + ad0 + ev.x);
        float c1 = LRELU(as.y + ad1 + ev.y);
        float c2 = LRELU(as.z + ad2 + ev.z);
        float c3 = LRELU(as.w + ad3 + ev.w);
        UPD(m0, s0, c0); UPD(m1, s1, c1); UPD(m2, s2, c2); UPD(m3, s3, c3);
    }
    #pragma unroll
    for (int off = 16; off >= 1; off >>= 1) {   // butterfly within 32-lane half
        COMB(m0, s0, off); COMB(m1, s1, off);
        COMB(m2, s2, off); COMB(m3, s3, off);
    }
    m0 = fmaxf(m0, -1e9f); m1 = fmaxf(m1, -1e9f);
    m2 = fmaxf(m2, -1e9f); m3 = fmaxf(m3, -1e9f);

    // ---- pass 2: 4 edge-groups of 8 lanes per half; lane owns 16 dims ----
    int g  = l5 >> 3;            // edge group 0..3
    int sl = l5 & 7;             // sub-lane: dims sl*16 .. sl*16+15
    int headL = sl >> 1;         // head of this lane's dims

    float m_h  = (headL & 2) ? ((headL & 1) ? m3 : m2) : ((headL & 1) ? m1 : m0);
    float s_h  = (headL & 2) ? ((headL & 1) ? s3 : s2) : ((headL & 1) ? s1 : s0);
    float ad_h = (headL & 2) ? ((headL & 1) ? ad3 : ad2) : ((headL & 1) ? ad1 : ad0);
    float rs = 1.0f / (s_h + 1e-10f);
    float et0 = etab[0 * 4 + headL];
    float et1 = etab[1 * 4 + headL];
    float et2 = etab[2 * 4 + headL];

    float acc[16];
    #pragma unroll
    for (int k = 0; k < 16; ++k) acc[k] = 0.f;

    for (int j = g; j < deg; j += 4) {
        unsigned int p = epack[e0 + j];
        int si = p & 0xFFFF;
        int t  = p >> 16;
        float asv = alpha_src[(size_t)si * 4 + headL];
        float ev  = (t == 0) ? et0 : ((t == 1) ? et1 : et2);
        float c = LRELU(asv + ad_h + ev);
        float w = __expf(c - m_h) * rs;
        const uint4* hp = (const uint4*)(hb + ((size_t)si << 7) + (sl << 4));
        uint4 h0 = hp[0];
        uint4 h1 = hp[1];
        acc[0]  += w * BFLO(h0.x); acc[1]  += w * BFHI(h0.x);
        acc[2]  += w * BFLO(h0.y); acc[3]  += w * BFHI(h0.y);
        acc[4]  += w * BFLO(h0.z); acc[5]  += w * BFHI(h0.z);
        acc[6]  += w * BFLO(h0.w); acc[7]  += w * BFHI(h0.w);
        acc[8]  += w * BFLO(h1.x); acc[9]  += w * BFHI(h1.x);
        acc[10] += w * BFLO(h1.y); acc[11] += w * BFHI(h1.y);
        acc[12] += w * BFLO(h1.z); acc[13] += w * BFHI(h1.z);
        acc[14] += w * BFLO(h1.w); acc[15] += w * BFHI(h1.w);
    }
    // combine the 4 edge-groups (xor bits 3,4 of lane)
    #pragma unroll
    for (int k = 0; k < 16; ++k) {
        acc[k] += __shfl_xor(acc[k], 8);
        acc[k] += __shfl_xor(acc[k], 16);
    }

    // ---- epilogue: residual + LayerNorm (16 dims per lane, dup x4) ----
    const uint4* rp = (const uint4*)(hb + ((size_t)n << 7) + (sl << 4));
    uint4 r0 = rp[0];
    uint4 r1 = rp[1];
    float o[16];
    o[0]  = acc[0]  + BFLO(r0.x); o[1]  = acc[1]  + BFHI(r0.x);
    o[2]  = acc[2]  + BFLO(r0.y); o[3]  = acc[3]  + BFHI(r0.y);
    o[4]  = acc[4]  + BFLO(r0.z); o[5]  = acc[5]  + BFHI(r0.z);
    o[6]  = acc[6]  + BFLO(r0.w); o[7]  = acc[7]  + BFHI(r0.w);
    o[8]  = acc[8]  + BFLO(r1.x); o[9]  = acc[9]  + BFHI(r1.x);
    o[10] = acc[10] + BFLO(r1.y); o[11] = acc[11] + BFHI(r1.y);
    o[12] = acc[12] + BFLO(r1.z); o[13] = acc[13] + BFHI(r1.z);
    o[14] = acc[14] + BFLO(r1.w); o[15] = acc[15] + BFHI(r1.w);

    float lsum = 0.f;
    #pragma unroll
    for (int k = 0; k < 16; ++k) lsum += o[k];
    #pragma unroll
    for (int off = 4; off >= 1; off >>= 1) lsum += __shfl_xor(lsum, off);
    float mean = lsum * (1.0f / 128.0f);
    float vs = 0.f;
    #pragma unroll
    for (int k = 0; k < 16; ++k) { float d = o[k] - mean; vs += d * d; }
    #pragma unroll
    for (int off = 4; off >= 1; off >>= 1) vs += __shfl_xor(vs, off);
    float inv = rsqrtf(vs * (1.0f / 128.0f) + LN_EPS);

    // each lane finalizes and writes its group's float4 slice
    float4 gv = *(const float4*)(gamma + sl * 16 + g * 4);
    float4 bv = *(const float4*)(beta  + sl * 16 + g * 4);
    float4 wv;
    wv.x = (o[g * 4 + 0] - mean) * inv * gv.x + bv.x;
    wv.y = (o[g * 4 + 1] - mean) * inv * gv.y + bv.y;
    wv.z = (o[g * 4 + 2] - mean) * inv * gv.z + bv.z;
    wv.w = (o[g * 4 + 3] - mean) * inv * gv.w + bv.w;
    *(float4*)(out + (size_t)n * OUT_DIM + sl * 16 + g * 4) = wv;
}

// ---------------------------------------------------------------------------
extern "C" void kernel_launch(void* const* d_in, const int* in_sizes, int n_in,
                              void* d_out, int out_size, void* d_ws, size_t ws_size,
                              hipStream_t stream)
{
    const float* x          = (const float*)d_in[0];
    const int*   edge_index = (const int*)d_in[1];
    const int*   etype      = (const int*)d_in[2];
    const float* W          = (const float*)d_in[3];
    const float* a_src      = (const float*)d_in[4];
    const float* a_dst      = (const float*)d_in[5];
    const float* a_edge     = (const float*)d_in[6];
    const float* edge_embed = (const float*)d_in[7];
    const float* gamma      = (const float*)d_in[8];
    const float* beta       = (const float*)d_in[9];

    float* ws = (float*)d_ws;
    unsigned short* hb = (unsigned short*)(ws + WS_HB);
    float* asrc = ws + WS_ASRC;
    float* adst = ws + WS_ADST;
    float* etab = ws + WS_ETAB;
    int*   deg  = (int*)d_ws + WS_DEG;
    int*   cur  = (int*)d_ws + WS_CUR;
    int*   offs = (int*)d_ws + WS_OFFS;
    int*   parts= (int*)d_ws + WS_PARTS;
    unsigned int* epack = (unsigned int*)d_ws + WS_EPACK;

    const int* srcs = edge_index;
    const int* dsts = edge_index + N_EDGES;

    hipMemsetAsync(deg, 0, 2 * N_NODES * sizeof(int), stream);  // deg + cur

    gemm_alpha_kernel<<<512, 256, 0, stream>>>(x, W, a_src, a_dst, hb, asrc, adst);
    count_kernel<<<(N_EDGES + 255) / 256, 256, 0, stream>>>(dsts, deg, edge_embed, a_edge, etab);
    scan_part_kernel<<<SCAN_BLOCKS, 1024, 0, stream>>>(deg, offs, parts);
    scan_tops_kernel<<<1, 64, 0, stream>>>(parts, offs + N_NODES);
    scan_add_kernel<<<SCAN_BLOCKS, 1024, 0, stream>>>(offs, parts);
    fill_kernel<<<(N_EDGES + 255) / 256, 256, 0, stream>>>(srcs, dsts, etype, offs, cur, epack);
    aggregate_kernel<<<(N_NODES + 7) / 8, 256, 0, stream>>>(
        hb, asrc, adst, etab, epack, offs, gamma, beta, (float*)d_out);
}

// Round 4
// 151.542 us; speedup vs baseline: 2.8357x; 1.3116x over previous
//
#include <hip/hip_runtime.h>

#define N_NODES 50000
#define N_EDGES 800000
#define IN_DIM 128
#define OUT_DIM 128
#define N_HEADS 4
#define HEAD_DIM 32
#define LN_EPS 1e-5f

// ws layout (f32-element offsets)
#define WS_HB    0          // 3,200,000 f32 slots = 6.4M ushort (h in bf16)
#define WS_ASRC  3200000    // 200000 f32
#define WS_ADST  3400000    // 200000 f32
#define WS_ETAB  3600000    // 16 f32
#define WS_DEG   3600016    // 50000 int
#define WS_CUR   3650016    // 50000 int   (DEG..AVTAB zeroed in one memset)
#define WS_AVTAB 3700016    // 2048 ushort = 512 f32 slots (av fragments, bf16)
#define WS_OFFS  3700528    // 50001 int (pad to 50004)
#define WS_PARTS 3750532    // 64 int
#define WS_EPACK 3750596    // 800000 u32 (src | etype<<16, sorted by dst)

#define SCAN_BLOCKS 49      // ceil(50000/1024)

typedef __bf16 bf16x8 __attribute__((ext_vector_type(8)));
typedef float  f32x4  __attribute__((ext_vector_type(4)));

__device__ __forceinline__ unsigned short f2bf(float f) {
    unsigned int u = __float_as_uint(f);
    u += 0x7FFF + ((u >> 16) & 1);          // round-to-nearest-even
    return (unsigned short)(u >> 16);
}
#define BFLO(u) __uint_as_float((unsigned int)(u) << 16)
#define BFHI(u) __uint_as_float((unsigned int)(u) & 0xFFFF0000u)

// ---------------- prep: etab + av table (bf16 fragment layout) -------------
// av[k][c8] = sum_dd W[hh*32+dd][k] * a[c8][dd];  c8<4 -> a_src head c8,
// c8 in 4..7 -> a_dst head c8-4.  Stored as bf16x8 frags [kblk][lane][j]:
// lane = g*16 + c8 (g = (k&31)>>3), j = k&7, kblk = k>>5. Unused lanes
// (lane&15 >= 8) are pre-zeroed by the memset.
__global__ __launch_bounds__(256) void prep_kernel(
    const float* __restrict__ W, const float* __restrict__ a_src,
    const float* __restrict__ a_dst, const float* __restrict__ edge_embed,
    const float* __restrict__ a_edge, float* __restrict__ etab,
    unsigned short* __restrict__ avtab)
{
    int gid = blockIdx.x * 256 + threadIdx.x;
    if (gid < 12) {
        int t = gid >> 2, hh = gid & 3;
        float s = 0.f;
        for (int k = 0; k < 16; ++k) s += edge_embed[t * 16 + k] * a_edge[hh * 16 + k];
        etab[gid] = s;
    }
    if (gid < 1024) {
        int c8 = gid & 7, k = gid >> 3;
        int hh = c8 & 3;
        const float* av = (c8 < 4) ? a_src : a_dst;
        float s = 0.f;
        #pragma unroll 8
        for (int dd = 0; dd < 32; ++dd)
            s += W[(hh * 32 + dd) * 128 + k] * av[hh * 32 + dd];
        int kblk = k >> 5, g = (k & 31) >> 3, j = k & 7;
        avtab[((kblk * 64) + g * 16 + c8) * 8 + j] = f2bf(s);
    }
}

// ---------------- K1: MFMA GEMM  h(bf16) = x @ W^T  + alpha ---------------
__global__ __launch_bounds__(256) void gemm_mfma_kernel(
    const float* __restrict__ x, const float* __restrict__ W,
    const unsigned short* __restrict__ avtab,
    unsigned short* __restrict__ hb,
    float* __restrict__ alpha_src, float* __restrict__ alpha_dst)
{
    // W fragments: wlds[(ct*4+kb)*64 + lane], lane holds W[ct*16+(lane&15)]
    // [kb*32 + (lane>>4)*8 + j]  (same k-assignment as A frags -> consistent)
    __shared__ bf16x8 wlds[2048];   // 32 KB
    int tid = threadIdx.x;
    for (int f = tid; f < 2048; f += 256) {
        int ct = f >> 8, kb = (f >> 6) & 3, ln = f & 63;
        int d = ct * 16 + (ln & 15);
        int kbase = kb * 32 + ((ln >> 4) << 3);
        const float* wp = W + d * 128 + kbase;
        float4 w0 = *(const float4*)wp;
        float4 w1 = *(const float4*)(wp + 4);
        bf16x8 v;
        v[0] = (__bf16)w0.x; v[1] = (__bf16)w0.y; v[2] = (__bf16)w0.z; v[3] = (__bf16)w0.w;
        v[4] = (__bf16)w1.x; v[5] = (__bf16)w1.y; v[6] = (__bf16)w1.z; v[7] = (__bf16)w1.w;
        wlds[f] = v;
    }
    int lane = tid & 63, wid = tid >> 6;
    bf16x8 avf[4];
    const bf16x8* avp = (const bf16x8*)avtab;
    #pragma unroll
    for (int kb = 0; kb < 4; ++kb) avf[kb] = avp[kb * 64 + lane];
    __syncthreads();

    int r = lane & 15, g = lane >> 4;
    for (int tile = blockIdx.x * 4 + wid; tile < N_NODES / 16; tile += gridDim.x * 4) {
        const float* xp = x + ((size_t)tile * 16 + r) * 128 + g * 8;
        bf16x8 af[4];
        #pragma unroll
        for (int kb = 0; kb < 4; ++kb) {
            float4 x0 = *(const float4*)(xp + kb * 32);
            float4 x1 = *(const float4*)(xp + kb * 32 + 4);
            bf16x8 v;
            v[0] = (__bf16)x0.x; v[1] = (__bf16)x0.y; v[2] = (__bf16)x0.z; v[3] = (__bf16)x0.w;
            v[4] = (__bf16)x1.x; v[5] = (__bf16)x1.y; v[6] = (__bf16)x1.z; v[7] = (__bf16)x1.w;
            af[kb] = v;
        }
        // alpha: [16 rows x 8 cols] (cols 0-3 src heads, 4-7 dst heads)
        f32x4 aacc = {0.f, 0.f, 0.f, 0.f};
        #pragma unroll
        for (int kb = 0; kb < 4; ++kb)
            aacc = __builtin_amdgcn_mfma_f32_16x16x32_bf16(af[kb], avf[kb], aacc, 0, 0, 0);

        int orow = tile * 16 + g * 4;   // C/D: row = g*4+q, col = ct*16+r
        #pragma unroll
        for (int ct = 0; ct < 8; ++ct) {
            f32x4 acc = {0.f, 0.f, 0.f, 0.f};
            #pragma unroll
            for (int kb = 0; kb < 4; ++kb)
                acc = __builtin_amdgcn_mfma_f32_16x16x32_bf16(af[kb], wlds[(ct * 4 + kb) * 64 + lane], acc, 0, 0, 0);
            #pragma unroll
            for (int q = 0; q < 4; ++q)
                hb[(size_t)(orow + q) * 128 + ct * 16 + r] = f2bf(acc[q]);
        }
        if (r < 8) {
            float* ap = (r < 4) ? (alpha_src + (r & 3)) : (alpha_dst + (r & 3));
            #pragma unroll
            for (int q = 0; q < 4; ++q)
                ap[(size_t)(orow + q) * 4] = aacc[q];
        }
    }
}

// ---------------- CSR build ------------------------------------------------
__global__ void count_kernel(const int* __restrict__ dst, int* __restrict__ deg)
{
    int e = blockIdx.x * 256 + threadIdx.x;
    if (e < N_EDGES) atomicAdd(&deg[dst[e]], 1);
}

__global__ __launch_bounds__(1024) void scan_part_kernel(
    const int* __restrict__ deg, int* __restrict__ offs, int* __restrict__ parts)
{
    __shared__ int wsum[16];
    int i = blockIdx.x * 1024 + threadIdx.x;
    int lane = threadIdx.x & 63;
    int wid  = threadIdx.x >> 6;
    int v = (i < N_NODES) ? deg[i] : 0;
    int xinc = v;
    #pragma unroll
    for (int d = 1; d < 64; d <<= 1) {
        int y = __shfl_up(xinc, d);
        if (lane >= d) xinc += y;
    }
    if (lane == 63) wsum[wid] = xinc;
    __syncthreads();
    if (wid == 0) {
        int sv = (lane < 16) ? wsum[lane] : 0;
        #pragma unroll
        for (int d = 1; d < 16; d <<= 1) {
            int y = __shfl_up(sv, d);
            if (lane >= d) sv += y;
        }
        if (lane < 16) wsum[lane] = sv;
    }
    __syncthreads();
    int woff = (wid > 0) ? wsum[wid - 1] : 0;
    if (i < N_NODES) offs[i] = woff + xinc - v;   // tile-local exclusive
    if (threadIdx.x == 0) parts[blockIdx.x] = wsum[15];
}

__global__ void scan_tops_kernel(int* __restrict__ parts, int* __restrict__ offs_last)
{
    int lane = threadIdx.x;  // 64 threads
    int v = (lane < SCAN_BLOCKS) ? parts[lane] : 0;
    int xv = v;
    #pragma unroll
    for (int d = 1; d < 64; d <<= 1) {
        int y = __shfl_up(xv, d);
        if (lane >= d) xv += y;
    }
    if (lane < SCAN_BLOCKS) parts[lane] = xv - v;  // exclusive
    if (lane == 63) *offs_last = xv;               // grand total
}

__global__ __launch_bounds__(1024) void scan_add_kernel(
    int* __restrict__ offs, const int* __restrict__ parts)
{
    int i = blockIdx.x * 1024 + threadIdx.x;
    if (i < N_NODES) offs[i] += parts[blockIdx.x];
}

__global__ void fill_kernel(const int* __restrict__ srcs, const int* __restrict__ dsts,
                            const int* __restrict__ etype,
                            const int* __restrict__ offs,
                            int* __restrict__ cur, unsigned int* __restrict__ epack)
{
    int e = blockIdx.x * 256 + threadIdx.x;
    if (e < N_EDGES) {
        int d = dsts[e];
        int p = atomicAdd(&cur[d], 1);
        epack[offs[d] + p] = (unsigned int)srcs[e] | ((unsigned int)etype[e] << 16);
    }
}

// ---------------- K5: softmax + aggregate + residual + LayerNorm ----------
#define LRELU(c) ((c) > 0.f ? (c) : 0.2f * (c))
#define UPD(m, s, c) { float nm = fmaxf(m, c); s = s * __expf(m - nm) + __expf((c) - nm); m = nm; }
#define COMB(m, s, off) { float om_ = __shfl_xor(m, off); float os_ = __shfl_xor(s, off); \
                          float nm_ = fmaxf(m, om_); \
                          s = s * __expf(m - nm_) + os_ * __expf(om_ - nm_); m = nm_; }

__global__ __launch_bounds__(256) void aggregate_kernel(
    const unsigned short* __restrict__ hb, const float* __restrict__ alpha_src,
    const float* __restrict__ alpha_dst, const float* __restrict__ etab,
    const unsigned int* __restrict__ epack, const int* __restrict__ offs,
    const float* __restrict__ gamma, const float* __restrict__ beta,
    float* __restrict__ out)
{
    int lane = threadIdx.x & 63;
    int wid  = threadIdx.x >> 6;
    int half = lane >> 5;              // two nodes per wave
    int l5   = lane & 31;
    int n = blockIdx.x * 8 + wid * 2 + half;
    if (n >= N_NODES) return;

    int e0 = offs[n], deg = offs[n + 1] - e0;

    float4 adv = *(const float4*)(alpha_dst + (size_t)n * 4);
    float ad0 = adv.x, ad1 = adv.y, ad2 = adv.z, ad3 = adv.w;

    // ---- pass 1: per-head online (max, sum), 32 lanes over edges ----
    float m0 = -1e30f, m1 = -1e30f, m2 = -1e30f, m3 = -1e30f;
    float s0 = 0.f, s1 = 0.f, s2 = 0.f, s3 = 0.f;
    for (int j = l5; j < deg; j += 32) {
        unsigned int p = epack[e0 + j];
        int si = p & 0xFFFF;
        int t  = p >> 16;
        float4 as = *(const float4*)(alpha_src + (size_t)si * 4);
        float4 ev = *(const float4*)(etab + t * 4);
        float c0 = LRELU(as.x + ad0 + ev.x);
        float c1 = LRELU(as.y + ad1 + ev.y);
        float c2 = LRELU(as.z + ad2 + ev.z);
        float c3 = LRELU(as.w + ad3 + ev.w);
        UPD(m0, s0, c0); UPD(m1, s1, c1); UPD(m2, s2, c2); UPD(m3, s3, c3);
    }
    #pragma unroll
    for (int off = 16; off >= 1; off >>= 1) {   // butterfly within 32-lane half
        COMB(m0, s0, off); COMB(m1, s1, off);
        COMB(m2, s2, off); COMB(m3, s3, off);
    }
    m0 = fmaxf(m0, -1e9f); m1 = fmaxf(m1, -1e9f);
    m2 = fmaxf(m2, -1e9f); m3 = fmaxf(m3, -1e9f);

    // ---- pass 2: 4 edge-groups of 8 lanes per half; lane owns 16 dims ----
    int g  = l5 >> 3;            // edge group 0..3
    int sl = l5 & 7;             // sub-lane: dims sl*16 .. sl*16+15
    int headL = sl >> 1;         // head of this lane's dims

    float m_h  = (headL & 2) ? ((headL & 1) ? m3 : m2) : ((headL & 1) ? m1 : m0);
    float s_h  = (headL & 2) ? ((headL & 1) ? s3 : s2) : ((headL & 1) ? s1 : s0);
    float ad_h = (headL & 2) ? ((headL & 1) ? ad3 : ad2) : ((headL & 1) ? ad1 : ad0);
    float rs = 1.0f / (s_h + 1e-10f);
    float et0 = etab[0 * 4 + headL];
    float et1 = etab[1 * 4 + headL];
    float et2 = etab[2 * 4 + headL];

    float acc[16];
    #pragma unroll
    for (int k = 0; k < 16; ++k) acc[k] = 0.f;

    for (int j = g; j < deg; j += 4) {
        unsigned int p = epack[e0 + j];
        int si = p & 0xFFFF;
        int t  = p >> 16;
        float asv = alpha_src[(size_t)si * 4 + headL];
        float ev  = (t == 0) ? et0 : ((t == 1) ? et1 : et2);
        float c = LRELU(asv + ad_h + ev);
        float w = __expf(c - m_h) * rs;
        const uint4* hp = (const uint4*)(hb + ((size_t)si << 7) + (sl << 4));
        uint4 h0 = hp[0];
        uint4 h1 = hp[1];
        acc[0]  += w * BFLO(h0.x); acc[1]  += w * BFHI(h0.x);
        acc[2]  += w * BFLO(h0.y); acc[3]  += w * BFHI(h0.y);
        acc[4]  += w * BFLO(h0.z); acc[5]  += w * BFHI(h0.z);
        acc[6]  += w * BFLO(h0.w); acc[7]  += w * BFHI(h0.w);
        acc[8]  += w * BFLO(h1.x); acc[9]  += w * BFHI(h1.x);
        acc[10] += w * BFLO(h1.y); acc[11] += w * BFHI(h1.y);
        acc[12] += w * BFLO(h1.z); acc[13] += w * BFHI(h1.z);
        acc[14] += w * BFLO(h1.w); acc[15] += w * BFHI(h1.w);
    }
    // combine the 4 edge-groups (xor bits 3,4 of lane)
    #pragma unroll
    for (int k = 0; k < 16; ++k) {
        acc[k] += __shfl_xor(acc[k], 8);
        acc[k] += __shfl_xor(acc[k], 16);
    }

    // ---- epilogue: residual + LayerNorm (16 dims per lane, dup x4) ----
    const uint4* rp = (const uint4*)(hb + ((size_t)n << 7) + (sl << 4));
    uint4 r0 = rp[0];
    uint4 r1 = rp[1];
    float o[16];
    o[0]  = acc[0]  + BFLO(r0.x); o[1]  = acc[1]  + BFHI(r0.x);
    o[2]  = acc[2]  + BFLO(r0.y); o[3]  = acc[3]  + BFHI(r0.y);
    o[4]  = acc[4]  + BFLO(r0.z); o[5]  = acc[5]  + BFHI(r0.z);
    o[6]  = acc[6]  + BFLO(r0.w); o[7]  = acc[7]  + BFHI(r0.w);
    o[8]  = acc[8]  + BFLO(r1.x); o[9]  = acc[9]  + BFHI(r1.x);
    o[10] = acc[10] + BFLO(r1.y); o[11] = acc[11] + BFHI(r1.y);
    o[12] = acc[12] + BFLO(r1.z); o[13] = acc[13] + BFHI(r1.z);
    o[14] = acc[14] + BFLO(r1.w); o[15] = acc[15] + BFHI(r1.w);

    float lsum = 0.f;
    #pragma unroll
    for (int k = 0; k < 16; ++k) lsum += o[k];
    #pragma unroll
    for (int off = 4; off >= 1; off >>= 1) lsum += __shfl_xor(lsum, off);
    float mean = lsum * (1.0f / 128.0f);
    float vs = 0.f;
    #pragma unroll
    for (int k = 0; k < 16; ++k) { float d = o[k] - mean; vs += d * d; }
    #pragma unroll
    for (int off = 4; off >= 1; off >>= 1) vs += __shfl_xor(vs, off);
    float inv = rsqrtf(vs * (1.0f / 128.0f) + LN_EPS);

    // each lane finalizes and writes its group's float4 slice
    float4 gv = *(const float4*)(gamma + sl * 16 + g * 4);
    float4 bv = *(const float4*)(beta  + sl * 16 + g * 4);
    float4 wv;
    wv.x = (o[g * 4 + 0] - mean) * inv * gv.x + bv.x;
    wv.y = (o[g * 4 + 1] - mean) * inv * gv.y + bv.y;
    wv.z = (o[g * 4 + 2] - mean) * inv * gv.z + bv.z;
    wv.w = (o[g * 4 + 3] - mean) * inv * gv.w + bv.w;
    *(float4*)(out + (size_t)n * OUT_DIM + sl * 16 + g * 4) = wv;
}

// ---------------------------------------------------------------------------
extern "C" void kernel_launch(void* const* d_in, const int* in_sizes, int n_in,
                              void* d_out, int out_size, void* d_ws, size_t ws_size,
                              hipStream_t stream)
{
    const float* x          = (const float*)d_in[0];
    const int*   edge_index = (const int*)d_in[1];
    const int*   etype      = (const int*)d_in[2];
    const float* W          = (const float*)d_in[3];
    const float* a_src      = (const float*)d_in[4];
    const float* a_dst      = (const float*)d_in[5];
    const float* a_edge     = (const float*)d_in[6];
    const float* edge_embed = (const float*)d_in[7];
    const float* gamma      = (const float*)d_in[8];
    const float* beta       = (const float*)d_in[9];

    float* ws = (float*)d_ws;
    unsigned short* hb = (unsigned short*)(ws + WS_HB);
    float* asrc = ws + WS_ASRC;
    float* adst = ws + WS_ADST;
    float* etab = ws + WS_ETAB;
    int*   deg  = (int*)d_ws + WS_DEG;
    int*   cur  = (int*)d_ws + WS_CUR;
    unsigned short* avtab = (unsigned short*)((int*)d_ws + WS_AVTAB);
    int*   offs = (int*)d_ws + WS_OFFS;
    int*   parts= (int*)d_ws + WS_PARTS;
    unsigned int* epack = (unsigned int*)d_ws + WS_EPACK;

    const int* srcs = edge_index;
    const int* dsts = edge_index + N_EDGES;

    // zero deg + cur + avtab in one shot (contiguous)
    hipMemsetAsync(deg, 0, (2 * N_NODES) * sizeof(int) + 2048 * sizeof(unsigned short), stream);

    prep_kernel<<<4, 256, 0, stream>>>(W, a_src, a_dst, edge_embed, a_edge, etab, avtab);
    gemm_mfma_kernel<<<512, 256, 0, stream>>>(x, W, avtab, hb, asrc, adst);
    count_kernel<<<(N_EDGES + 255) / 256, 256, 0, stream>>>(dsts, deg);
    scan_part_kernel<<<SCAN_BLOCKS, 1024, 0, stream>>>(deg, offs, parts);
    scan_tops_kernel<<<1, 64, 0, stream>>>(parts, offs + N_NODES);
    scan_add_kernel<<<SCAN_BLOCKS, 1024, 0, stream>>>(offs, parts);
    fill_kernel<<<(N_EDGES + 255) / 256, 256, 0, stream>>>(srcs, dsts, etype, offs, cur, epack);
    aggregate_kernel<<<(N_NODES + 7) / 8, 256, 0, stream>>>(
        hb, asrc, adst, etab, epack, offs, gamma, beta, (float*)d_out);
}